// Round 9
// baseline (267.087 us; speedup 1.0000x reference)
//
#include <hip/hip_runtime.h>
#include <cstdint>
#include <cstddef>

// ---------------------------------------------------------------------------
// GCN encoder:
//   g[u]  = dinv[u] * h[u]    (folded into GEMM epilogue, bf16, SLICE-MAJOR)
//   out[v]= dinv[v] * (sum_{e:dst=v} g[src] + g[v]) + b
// r9: slices widened to 64 channels -> 128B line-aligned rows (2x bytes per
// L1 miss slot; tests MSHR/line-size bound). Slice = 6.4MB, partially
// L2-resident; slice s maps to XCDs {s, s+NSL, ...} via bid%8 with a
// bijective duplicate-index so each (node-block, slice) runs exactly once.
// ---------------------------------------------------------------------------

static constexpr int CH1 = 256;
static constexpr int CH2 = 128;

typedef __attribute__((ext_vector_type(8))) short bf16x8;
typedef __attribute__((ext_vector_type(4))) float f32x4;
typedef __attribute__((ext_vector_type(4))) unsigned short u16x4;
typedef __attribute__((ext_vector_type(8))) unsigned short u16x8;

__device__ inline unsigned short f2bf(float f) {  // round-to-nearest-even
  unsigned u = __builtin_bit_cast(unsigned, f);
  return (unsigned short)((u + 0x7fffu + ((u >> 16) & 1u)) >> 16);
}
__device__ inline float bf2f(unsigned short h) {
  return __builtin_bit_cast(float, (unsigned)h << 16);
}
__device__ inline float lo16(unsigned u) { return __builtin_bit_cast(float, u << 16); }
__device__ inline float hi16(unsigned u) { return __builtin_bit_cast(float, u & 0xffff0000u); }

__device__ inline void gload16(const void* g, void* l) {
  __builtin_amdgcn_global_load_lds(
      (const __attribute__((address_space(1))) unsigned int*)g,
      (__attribute__((address_space(3))) unsigned int*)l, 16, 0, 0);
}

// ---------------- preprocessing --------------------------------------------

__global__ void k_init_deg(int* __restrict__ deg, int n, int* __restrict__ flag) {
  int i = blockIdx.x * blockDim.x + threadIdx.x;
  if (i < n) deg[i] = 0;
  if (i == 0) *flag = 0;
}

__global__ void k_detect_i32(const unsigned int* __restrict__ w, int nwords,
                             int* __restrict__ flag) {
  int i = blockIdx.x * blockDim.x + threadIdx.x;
  if (i < nwords && (i & 1) && w[i] != 0u) *flag = 1;
}

// fused convert + degree count (deg must be pre-zeroed)
__global__ void k_cvt_deg(const void* __restrict__ raw, int* __restrict__ e32,
                          int* __restrict__ deg, int E, const int* __restrict__ flag) {
  int i = blockIdx.x * blockDim.x + threadIdx.x;
  if (i >= 2 * E) return;
  int v = (*flag) ? ((const int*)raw)[i] : (int)((const long long*)raw)[i];
  e32[i] = v;
  if (i >= E) atomicAdd(&deg[v], 1);  // dst half
}

__global__ __launch_bounds__(256) void k_chunk_sum(const int* __restrict__ deg,
                                                   int* __restrict__ bsum, int N) {
  __shared__ int sh[256];
  int i = blockIdx.x * 256 + threadIdx.x;
  sh[threadIdx.x] = (i < N) ? deg[i] : 0;
  __syncthreads();
  for (int off = 128; off > 0; off >>= 1) {
    if (threadIdx.x < (unsigned)off) sh[threadIdx.x] += sh[threadIdx.x + off];
    __syncthreads();
  }
  if (threadIdx.x == 0) bsum[blockIdx.x] = sh[0];
}

__global__ __launch_bounds__(256) void k_scan_bsums(int* __restrict__ bsum, int nb) {
  __shared__ int sh[256];
  int t = threadIdx.x;
  int v = (t < nb) ? bsum[t] : 0;
  sh[t] = v;
  __syncthreads();
  for (int off = 1; off < 256; off <<= 1) {
    int add = (t >= off) ? sh[t - off] : 0;
    __syncthreads();
    sh[t] += add;
    __syncthreads();
  }
  if (t < nb) bsum[t] = sh[t] - v;  // exclusive
}

__global__ __launch_bounds__(256) void k_chunk_scan(
    const int* __restrict__ deg, const int* __restrict__ bsum,
    int* __restrict__ rowstart, int* __restrict__ cursor,
    float* __restrict__ dinv, int N, int E) {
  __shared__ int sh[256];
  int t = threadIdx.x;
  int i = blockIdx.x * 256 + t;
  int d = (i < N) ? deg[i] : 0;
  sh[t] = d;
  __syncthreads();
  for (int off = 1; off < 256; off <<= 1) {
    int add = (t >= off) ? sh[t - off] : 0;
    __syncthreads();
    sh[t] += add;
    __syncthreads();
  }
  if (i < N) {
    int rs = bsum[blockIdx.x] + sh[t] - d;
    rowstart[i] = rs;
    cursor[i]   = rs;
    dinv[i] = rsqrtf((float)(d + 1));  // +1: self-loop
  }
  if (i == 0) rowstart[N] = E;
}

__global__ void k_fill(const int* __restrict__ src, const int* __restrict__ dst,
                       int* __restrict__ cursor, int* __restrict__ csr, int E) {
  int e = blockIdx.x * blockDim.x + threadIdx.x;
  if (e < E) {
    int pos = atomicAdd(&cursor[dst[e]], 1);
    csr[pos] = src[e];
  }
}

// ---------------- fp32 -> bf16 hi/lo split ---------------------------------

__global__ void k_split4(const float4* __restrict__ in, u16x4* __restrict__ oh,
                         u16x4* __restrict__ ol, int n4) {
  int i = blockIdx.x * blockDim.x + threadIdx.x;
  if (i >= n4) return;
  float4 v = in[i];
  u16x4 h, l;
  h.x = f2bf(v.x); l.x = f2bf(v.x - bf2f(h.x));
  h.y = f2bf(v.y); l.y = f2bf(v.y - bf2f(h.y));
  h.z = f2bf(v.z); l.z = f2bf(v.z - bf2f(h.z));
  h.w = f2bf(v.w); l.w = f2bf(v.w - bf2f(h.w));
  oh[i] = h; ol[i] = l;
}

// Both weights W[K,N] fp32 -> W^T hi/lo bf16 [N,K], in one launch.
__global__ void k_splitT2(const float* __restrict__ Wa, unsigned short* __restrict__ ah,
                          unsigned short* __restrict__ al, int Ka, int Na,
                          const float* __restrict__ Wb, unsigned short* __restrict__ bh,
                          unsigned short* __restrict__ bl, int Kb, int Nb) {
  int idx = blockIdx.x * blockDim.x + threadIdx.x;
  int na = Ka * Na;
  if (idx < na) {
    int k = idx / Na, n = idx - k * Na;
    float v = Wa[idx];
    unsigned short h = f2bf(v);
    ah[(size_t)n * Ka + k] = h;
    al[(size_t)n * Ka + k] = f2bf(v - bf2f(h));
  } else {
    idx -= na;
    if (idx < Kb * Nb) {
      int k = idx / Nb, n = idx - k * Nb;
      float v = Wb[idx];
      unsigned short h = f2bf(v);
      bh[(size_t)n * Kb + k] = h;
      bl[(size_t)n * Kb + k] = f2bf(v - bf2f(h));
    }
  }
}

// ---------------------------------------------------------------------------
// Split-bf16 MFMA GEMM: C[M,BN] = A[M,K] @ B[K,BN], A row-major bf16
// (hi + optional lo), B as B^T (Bh+Bl) bf16 [BN,K].
// acc += AhBh + AhBl (+ AlBh if SPLITA). Epilogue: g = dinv[row]*acc, stored
// bf16 SLICE-MAJOR 64ch: Co[(col/64)*M*64 + row*64 + col%64].
// ---------------------------------------------------------------------------
template <int BN, bool SPLITA>
__global__ __launch_bounds__(256) void k_gemm_mfma(
    const unsigned short* __restrict__ Ah, const unsigned short* __restrict__ Al,
    const unsigned short* __restrict__ Bh, const unsigned short* __restrict__ Bl,
    const float* __restrict__ dinv, unsigned short* __restrict__ Co, int M, int K) {
  constexpr int BM = 64, BK = 32;
  constexpr int NF = BN / 64;          // B frags per wave (4 or 2)
  constexpr int ASZ = BM * BK;         // ushorts per A half
  constexpr int BSZ = BN * BK;         // ushorts per B half
  constexpr int AH = SPLITA ? 2 : 1;
  __shared__ unsigned short lds[2][AH * ASZ + 2 * BSZ];
  const int t = threadIdx.x;
  const int w = t >> 6, l = t & 63;
  const int m0 = blockIdx.x * BM;
  const int lr = l & 15, lk = l >> 4;

  auto stage = [&](int buf, int k0) {
    unsigned short* base = lds[buf];
    {  // A: 256 slots per half, one per thread; dest byte = t*16 (linear)
      int row = t >> 2, p = t & 3;
      int s = p ^ ((row >> 1) & 3);
      int gm = m0 + row; if (gm >= M) gm = M - 1;
      size_t go = (size_t)gm * K + k0 + s * 8;
      gload16(Ah + go, base + (size_t)row * BK + p * 8);
      if constexpr (SPLITA)
        gload16(Al + go, base + ASZ + (size_t)row * BK + p * 8);
    }
    for (int i = t; i < BN * 4; i += 256) {  // B: BN*4 slots per half
      int n = i >> 2, p = i & 3;
      int s = p ^ ((n >> 1) & 3);
      size_t go = (size_t)n * K + k0 + s * 8;
      gload16(Bh + go, base + AH * ASZ + (size_t)n * BK + p * 8);
      gload16(Bl + go, base + AH * ASZ + BSZ + (size_t)n * BK + p * 8);
    }
  };

  f32x4 acc[4][NF];
#pragma unroll
  for (int a = 0; a < 4; ++a)
#pragma unroll
    for (int b = 0; b < NF; ++b) acc[a][b] = (f32x4){0.f, 0.f, 0.f, 0.f};

  stage(0, 0);
  __syncthreads();
  const int nsteps = K / BK;
  for (int ks = 0; ks < nsteps; ++ks) {
    int cur = ks & 1;
    if (ks + 1 < nsteps) stage(cur ^ 1, (ks + 1) * BK);
    const unsigned short* base = lds[cur];
    bf16x8 ah[4], al[4], bh[NF], bl[NF];
#pragma unroll
    for (int fm = 0; fm < 4; ++fm) {
      int row = fm * 16 + lr;
      int p = lk ^ ((row >> 1) & 3);
      const unsigned short* a = base + row * BK + p * 8;
      ah[fm] = *(const bf16x8*)a;
      if constexpr (SPLITA) al[fm] = *(const bf16x8*)(a + ASZ);
    }
#pragma unroll
    for (int fb = 0; fb < NF; ++fb) {
      int n = w * (BN / 4) + fb * 16 + lr;
      int p = lk ^ ((n >> 1) & 3);
      const unsigned short* b = base + AH * ASZ + n * BK + p * 8;
      bh[fb] = *(const bf16x8*)b;
      bl[fb] = *(const bf16x8*)(b + BSZ);
    }
#pragma unroll
    for (int fm = 0; fm < 4; ++fm)
#pragma unroll
      for (int fb = 0; fb < NF; ++fb) {
        acc[fm][fb] = __builtin_amdgcn_mfma_f32_16x16x32_bf16(ah[fm], bh[fb], acc[fm][fb], 0, 0, 0);
        acc[fm][fb] = __builtin_amdgcn_mfma_f32_16x16x32_bf16(ah[fm], bl[fb], acc[fm][fb], 0, 0, 0);
        if constexpr (SPLITA)
          acc[fm][fb] = __builtin_amdgcn_mfma_f32_16x16x32_bf16(al[fm], bh[fb], acc[fm][fb], 0, 0, 0);
      }
    __syncthreads();
  }
  // epilogue: C/D layout col=lane&15, row=(lane>>4)*4+reg; g=dinv*acc, sliced
#pragma unroll
  for (int fm = 0; fm < 4; ++fm)
#pragma unroll
    for (int r = 0; r < 4; ++r) {
      int row = m0 + fm * 16 + lk * 4 + r;
      if (row < M) {
        float dv = dinv[row];
#pragma unroll
        for (int fb = 0; fb < NF; ++fb) {
          int col = w * (BN / 4) + fb * 16 + lr;
          size_t o = ((size_t)(col >> 6) * M + row) * 64 + (col & 63);
          Co[o] = f2bf(dv * acc[fm][fb][r]);
        }
      }
    }
}

// ---------------------------------------------------------------------------
// Slice-resident gather-aggregate over pre-scaled bf16 gS, 64-ch slices.
// 32 lanes per node: 4 sub-lanes (stride-4 edge partition) x 8 channel lanes
// (uint4 = 16B each -> 128B line-aligned slice row). v_dot2_f32_bf16 accum.
// Bijective block map: x=bid%8 -> slice=x&(NSL-1), dup=x>>log2(NSL);
// nb=(bid>>3)*DUP+dup. out = dinv[v]*(sum g[src] + g[v]) + b.
// MODE 0: fp32 out.  MODE 1: relu -> bf16 f1 (single precision).
// ---------------------------------------------------------------------------
template <int C, int MODE>
__global__ __launch_bounds__(256) void k_agg_slice(
    const int* __restrict__ rowstart, const int* __restrict__ csr,
    const float* __restrict__ dinv, const unsigned short* __restrict__ gS,
    const float* __restrict__ bias, float* __restrict__ out,
    unsigned short* __restrict__ of1, int N) {
  constexpr int NSL = C / 64;        // 4 (C=256) or 2 (C=128)
  constexpr int DUP = 8 / NSL;       // XCD duplicates per slice
  const int x = blockIdx.x & 7;
  const int slice = x & (NSL - 1);
  const int dup = x >> (NSL == 4 ? 2 : 1);
  const int nb = ((int)blockIdx.x >> 3) * DUP + dup;
  const int v = nb * 8 + ((int)threadIdx.x >> 5);
  if (v >= N) return;
  const int ln = threadIdx.x & 31;
  const int sub = ln >> 3;   // edge sub-stream 0..3
  const int l8 = ln & 7;     // channel octet 0..7
  const unsigned short* __restrict__ base = gS + (size_t)slice * N * 64 + l8 * 8;

  const unsigned selL = 0x00003f80u;  // bf16 pair (lo=1.0, hi=0.0)
  const unsigned selH = 0x3f800000u;  // bf16 pair (lo=0.0, hi=1.0)
  float acc[8] = {0.f, 0.f, 0.f, 0.f, 0.f, 0.f, 0.f, 0.f};
#define DOT2(k, word, sel) \
  asm("v_dot2_f32_bf16 %0, %1, %2, %0" : "+v"(acc[k]) : "v"(word), "v"(sel));
#define ACC8(u)                 \
  { DOT2(0, (u).x, selL) DOT2(1, (u).x, selH)  \
    DOT2(2, (u).y, selL) DOT2(3, (u).y, selH)  \
    DOT2(4, (u).z, selL) DOT2(5, (u).z, selH)  \
    DOT2(6, (u).w, selL) DOT2(7, (u).w, selH) }

  const int end = rowstart[v + 1];
  int j = rowstart[v] + sub;
  for (; j + 4 < end; j += 8) {  // 2 edges per iter per sub-stream
    int s0 = csr[j], s1 = csr[j + 4];
    uint4 r0 = *(const uint4*)(base + (size_t)s0 * 64);
    uint4 r1 = *(const uint4*)(base + (size_t)s1 * 64);
    ACC8(r0) ACC8(r1)
  }
  if (j < end) {
    uint4 r = *(const uint4*)(base + (size_t)csr[j] * 64);
    ACC8(r)
  }
  // reduce the 4 sub-streams within each 32-lane group
#pragma unroll
  for (int k = 0; k < 8; ++k) {
    acc[k] += __shfl_xor(acc[k], 8, 32);
    acc[k] += __shfl_xor(acc[k], 16, 32);
  }
  if (sub != 0) return;
  {  // self-loop
    uint4 r = *(const uint4*)(base + (size_t)v * 64);
    ACC8(r)
  }
#undef ACC8
#undef DOT2
  const float dv = dinv[v];
  const int c0 = slice * 64 + l8 * 8;
  const float4 bA = *(const float4*)(bias + c0);
  const float4 bB = *(const float4*)(bias + c0 + 4);
  float o[8];
  o[0] = dv * acc[0] + bA.x; o[1] = dv * acc[1] + bA.y;
  o[2] = dv * acc[2] + bA.z; o[3] = dv * acc[3] + bA.w;
  o[4] = dv * acc[4] + bB.x; o[5] = dv * acc[5] + bB.y;
  o[6] = dv * acc[6] + bB.z; o[7] = dv * acc[7] + bB.w;
  if constexpr (MODE == 1) {
    u16x8 p;
#pragma unroll
    for (int k = 0; k < 8; ++k) p[k] = f2bf(fmaxf(o[k], 0.f));
    *(u16x8*)(of1 + (size_t)v * C + c0) = p;
  } else {
    *(float4*)(out + (size_t)v * C + c0) = make_float4(o[0], o[1], o[2], o[3]);
    *(float4*)(out + (size_t)v * C + c0 + 4) = make_float4(o[4], o[5], o[6], o[7]);
  }
}

// ---------------------------------------------------------------------------

extern "C" void kernel_launch(void* const* d_in, const int* in_sizes, int n_in,
                              void* d_out, int out_size, void* d_ws, size_t ws_size,
                              hipStream_t stream) {
  const float* x  = (const float*)d_in[0];
  const void*  ei = d_in[1];
  const float* W1 = (const float*)d_in[2];
  const float* b1 = (const float*)d_in[3];
  const float* W2 = (const float*)d_in[4];
  const float* b2 = (const float*)d_in[5];
  float* out = (float*)d_out;

  const int N = in_sizes[0] / CH1;  // 50000
  const int E = in_sizes[1] / 2;    // 800000

  char* w = (char*)d_ws;
  size_t off = 0;
  auto alloc = [&](size_t bytes) -> void* {
    void* p = w + off;
    off += (bytes + 255) & ~(size_t)255;
    return p;
  };
  int*   deg      = (int*)alloc((size_t)N * 4);
  int*   flag     = (int*)alloc(256);
  int*   e32      = (int*)alloc((size_t)2 * E * 4);
  int*   rowstart = (int*)alloc((size_t)(N + 1) * 4);
  int*   cursor   = (int*)alloc((size_t)N * 4);
  int*   bsum     = (int*)alloc(256 * 4);
  int*   csr      = (int*)alloc((size_t)E * 4);
  float* dinv     = (float*)alloc((size_t)N * 4);
  unsigned short* xh  = (unsigned short*)alloc((size_t)N * CH1 * 2);  // also f1
  unsigned short* xl  = (unsigned short*)alloc((size_t)N * CH1 * 2);
  unsigned short* g1S = (unsigned short*)alloc((size_t)N * CH1 * 2);  // sliced
  unsigned short* g2S = (unsigned short*)alloc((size_t)N * CH2 * 2);  // sliced
  unsigned short* w1th = (unsigned short*)alloc((size_t)CH1 * CH1 * 2);
  unsigned short* w1tl = (unsigned short*)alloc((size_t)CH1 * CH1 * 2);
  unsigned short* w2th = (unsigned short*)alloc((size_t)CH1 * CH2 * 2);
  unsigned short* w2tl = (unsigned short*)alloc((size_t)CH1 * CH2 * 2);

  const int* srcI = e32;
  const int* dstI = e32 + E;

  dim3 blk(256);
  auto cdiv = [](long long a, long long b) { return (int)((a + b - 1) / b); };
  const int nchunks = cdiv(N, 256);
  const int nodeblk8 = cdiv(N, 8);  // 8 nodes per 256-thr block (32 lanes/node)

  // --- CSR build ----------------------------------------------------------
  k_init_deg<<<cdiv(N, 256), blk, 0, stream>>>(deg, N, flag);
  k_detect_i32<<<cdiv(2LL * E, 256), blk, 0, stream>>>((const unsigned int*)ei, 2 * E, flag);
  k_cvt_deg<<<cdiv(2LL * E, 256), blk, 0, stream>>>(ei, e32, deg, E, flag);
  k_chunk_sum<<<nchunks, blk, 0, stream>>>(deg, bsum, N);
  k_scan_bsums<<<1, blk, 0, stream>>>(bsum, nchunks);
  k_chunk_scan<<<nchunks, blk, 0, stream>>>(deg, bsum, rowstart, cursor, dinv, N, E);
  k_fill<<<cdiv(E, 256), blk, 0, stream>>>(srcI, dstI, cursor, csr, E);

  // --- input splits -------------------------------------------------------
  k_split4<<<cdiv((long long)N * CH1 / 4, 256), blk, 0, stream>>>(
      (const float4*)x, (u16x4*)xh, (u16x4*)xl, N * CH1 / 4);
  k_splitT2<<<cdiv(CH1 * CH1 + CH1 * CH2, 256), blk, 0, stream>>>(
      W1, w1th, w1tl, CH1, CH1, W2, w2th, w2tl, CH1, CH2);

  // --- layer 1: g1 = dinv*(x@W1) sliced ; f1 = relu(dv*sum+b1) bf16 -> xh --
  k_gemm_mfma<CH1, true><<<cdiv(N, 64), blk, 0, stream>>>(
      xh, xl, w1th, w1tl, dinv, g1S, N, CH1);
  k_agg_slice<CH1, 1><<<cdiv(nodeblk8, 2) * 8, blk, 0, stream>>>(
      rowstart, csr, dinv, g1S, b1, nullptr, xh, N);

  // --- layer 2: g2 = dinv*(f1@W2) sliced ; out = dv*sum+b2 ----------------
  k_gemm_mfma<CH2, false><<<cdiv(N, 64), blk, 0, stream>>>(
      xh, nullptr, w2th, w2tl, dinv, g2S, N, CH1);
  k_agg_slice<CH2, 0><<<cdiv(nodeblk8, 4) * 8, blk, 0, stream>>>(
      rowstart, csr, dinv, g2S, b2, out, nullptr, N);
}

// Round 10
// 252.728 us; speedup vs baseline: 1.0568x; 1.0568x over previous
//
#include <hip/hip_runtime.h>
#include <cstdint>
#include <cstddef>

// ---------------------------------------------------------------------------
// GCN encoder:
//   g[u]  = dinv[u] * h[u]    (folded into GEMM epilogue, bf16, SLICE-MAJOR)
//   out[v]= dinv[v] * (sum_{e:dst=v} g[src] + g[v]) + b
// r10: x stored as plain bf16 (lo-half dropped; W keeps hi/lo split ->
// GEMM error ~2e-3, within threshold). Aggregate unchanged from r9
// (64-ch slices; at per-CU miss-service floor ~11 B/cyc/CU, r7-r9 evidence).
// ---------------------------------------------------------------------------

static constexpr int CH1 = 256;
static constexpr int CH2 = 128;

typedef __attribute__((ext_vector_type(8))) short bf16x8;
typedef __attribute__((ext_vector_type(4))) float f32x4;
typedef __attribute__((ext_vector_type(4))) unsigned short u16x4;
typedef __attribute__((ext_vector_type(8))) unsigned short u16x8;

__device__ inline unsigned short f2bf(float f) {  // round-to-nearest-even
  unsigned u = __builtin_bit_cast(unsigned, f);
  return (unsigned short)((u + 0x7fffu + ((u >> 16) & 1u)) >> 16);
}
__device__ inline float bf2f(unsigned short h) {
  return __builtin_bit_cast(float, (unsigned)h << 16);
}
__device__ inline float lo16(unsigned u) { return __builtin_bit_cast(float, u << 16); }
__device__ inline float hi16(unsigned u) { return __builtin_bit_cast(float, u & 0xffff0000u); }

__device__ inline void gload16(const void* g, void* l) {
  __builtin_amdgcn_global_load_lds(
      (const __attribute__((address_space(1))) unsigned int*)g,
      (__attribute__((address_space(3))) unsigned int*)l, 16, 0, 0);
}

// ---------------- preprocessing --------------------------------------------

__global__ void k_init_deg(int* __restrict__ deg, int n, int* __restrict__ flag) {
  int i = blockIdx.x * blockDim.x + threadIdx.x;
  if (i < n) deg[i] = 0;
  if (i == 0) *flag = 0;
}

__global__ void k_detect_i32(const unsigned int* __restrict__ w, int nwords,
                             int* __restrict__ flag) {
  int i = blockIdx.x * blockDim.x + threadIdx.x;
  if (i < nwords && (i & 1) && w[i] != 0u) *flag = 1;
}

// fused convert + degree count (deg must be pre-zeroed)
__global__ void k_cvt_deg(const void* __restrict__ raw, int* __restrict__ e32,
                          int* __restrict__ deg, int E, const int* __restrict__ flag) {
  int i = blockIdx.x * blockDim.x + threadIdx.x;
  if (i >= 2 * E) return;
  int v = (*flag) ? ((const int*)raw)[i] : (int)((const long long*)raw)[i];
  e32[i] = v;
  if (i >= E) atomicAdd(&deg[v], 1);  // dst half
}

__global__ __launch_bounds__(256) void k_chunk_sum(const int* __restrict__ deg,
                                                   int* __restrict__ bsum, int N) {
  __shared__ int sh[256];
  int i = blockIdx.x * 256 + threadIdx.x;
  sh[threadIdx.x] = (i < N) ? deg[i] : 0;
  __syncthreads();
  for (int off = 128; off > 0; off >>= 1) {
    if (threadIdx.x < (unsigned)off) sh[threadIdx.x] += sh[threadIdx.x + off];
    __syncthreads();
  }
  if (threadIdx.x == 0) bsum[blockIdx.x] = sh[0];
}

__global__ __launch_bounds__(256) void k_scan_bsums(int* __restrict__ bsum, int nb) {
  __shared__ int sh[256];
  int t = threadIdx.x;
  int v = (t < nb) ? bsum[t] : 0;
  sh[t] = v;
  __syncthreads();
  for (int off = 1; off < 256; off <<= 1) {
    int add = (t >= off) ? sh[t - off] : 0;
    __syncthreads();
    sh[t] += add;
    __syncthreads();
  }
  if (t < nb) bsum[t] = sh[t] - v;  // exclusive
}

__global__ __launch_bounds__(256) void k_chunk_scan(
    const int* __restrict__ deg, const int* __restrict__ bsum,
    int* __restrict__ rowstart, int* __restrict__ cursor,
    float* __restrict__ dinv, int N, int E) {
  __shared__ int sh[256];
  int t = threadIdx.x;
  int i = blockIdx.x * 256 + t;
  int d = (i < N) ? deg[i] : 0;
  sh[t] = d;
  __syncthreads();
  for (int off = 1; off < 256; off <<= 1) {
    int add = (t >= off) ? sh[t - off] : 0;
    __syncthreads();
    sh[t] += add;
    __syncthreads();
  }
  if (i < N) {
    int rs = bsum[blockIdx.x] + sh[t] - d;
    rowstart[i] = rs;
    cursor[i]   = rs;
    dinv[i] = rsqrtf((float)(d + 1));  // +1: self-loop
  }
  if (i == 0) rowstart[N] = E;
}

__global__ void k_fill(const int* __restrict__ src, const int* __restrict__ dst,
                       int* __restrict__ cursor, int* __restrict__ csr, int E) {
  int e = blockIdx.x * blockDim.x + threadIdx.x;
  if (e < E) {
    int pos = atomicAdd(&cursor[dst[e]], 1);
    csr[pos] = src[e];
  }
}

// ---------------- fp32 -> bf16 --------------------------------------------

// x fp32 -> bf16 (RNE), 8 elements per thread.
__global__ void k_cvt_bf16(const float4* __restrict__ in, u16x8* __restrict__ o, int n8) {
  int i = blockIdx.x * blockDim.x + threadIdx.x;
  if (i >= n8) return;
  float4 a = in[i * 2], b = in[i * 2 + 1];
  u16x8 p;
  p[0] = f2bf(a.x); p[1] = f2bf(a.y); p[2] = f2bf(a.z); p[3] = f2bf(a.w);
  p[4] = f2bf(b.x); p[5] = f2bf(b.y); p[6] = f2bf(b.z); p[7] = f2bf(b.w);
  o[i] = p;
}

// Both weights W[K,N] fp32 -> W^T hi/lo bf16 [N,K], in one launch.
__global__ void k_splitT2(const float* __restrict__ Wa, unsigned short* __restrict__ ah,
                          unsigned short* __restrict__ al, int Ka, int Na,
                          const float* __restrict__ Wb, unsigned short* __restrict__ bh,
                          unsigned short* __restrict__ bl, int Kb, int Nb) {
  int idx = blockIdx.x * blockDim.x + threadIdx.x;
  int na = Ka * Na;
  if (idx < na) {
    int k = idx / Na, n = idx - k * Na;
    float v = Wa[idx];
    unsigned short h = f2bf(v);
    ah[(size_t)n * Ka + k] = h;
    al[(size_t)n * Ka + k] = f2bf(v - bf2f(h));
  } else {
    idx -= na;
    if (idx < Kb * Nb) {
      int k = idx / Nb, n = idx - k * Nb;
      float v = Wb[idx];
      unsigned short h = f2bf(v);
      bh[(size_t)n * Kb + k] = h;
      bl[(size_t)n * Kb + k] = f2bf(v - bf2f(h));
    }
  }
}

// ---------------------------------------------------------------------------
// bf16 MFMA GEMM with split-B: C[M,BN] = A[M,K] @ B[K,BN], A row-major bf16,
// B as B^T (Bh+Bl) bf16 [BN,K]. acc += A·Bh + A·Bl (fp32 accum).
// Epilogue: g = dinv[row]*acc, stored bf16 SLICE-MAJOR 64ch:
// Co[(col/64)*M*64 + row*64 + col%64].
// BM=64, BK=32, 256 threads (4 waves). LDS double-buffered, global_load_lds
// 16B staging, 16B-slot XOR swizzle -> 2-way-max ds conflicts.
// ---------------------------------------------------------------------------
template <int BN>
__global__ __launch_bounds__(256) void k_gemm_mfma(
    const unsigned short* __restrict__ A,
    const unsigned short* __restrict__ Bh, const unsigned short* __restrict__ Bl,
    const float* __restrict__ dinv, unsigned short* __restrict__ Co, int M, int K) {
  constexpr int BM = 64, BK = 32;
  constexpr int NF = BN / 64;          // B frags per wave (4 or 2)
  constexpr int ASZ = BM * BK;         // ushorts in A tile
  constexpr int BSZ = BN * BK;         // ushorts per B half
  __shared__ unsigned short lds[2][ASZ + 2 * BSZ];
  const int t = threadIdx.x;
  const int w = t >> 6, l = t & 63;
  const int m0 = blockIdx.x * BM;
  const int lr = l & 15, lk = l >> 4;

  auto stage = [&](int buf, int k0) {
    unsigned short* base = lds[buf];
    {  // A: 256 slots, one per thread; dest byte = t*16 (linear)
      int row = t >> 2, p = t & 3;
      int s = p ^ ((row >> 1) & 3);
      int gm = m0 + row; if (gm >= M) gm = M - 1;
      gload16(A + (size_t)gm * K + k0 + s * 8, base + (size_t)row * BK + p * 8);
    }
    for (int i = t; i < BN * 4; i += 256) {  // B: BN*4 slots per half
      int n = i >> 2, p = i & 3;
      int s = p ^ ((n >> 1) & 3);
      size_t go = (size_t)n * K + k0 + s * 8;
      gload16(Bh + go, base + ASZ + (size_t)n * BK + p * 8);
      gload16(Bl + go, base + ASZ + BSZ + (size_t)n * BK + p * 8);
    }
  };

  f32x4 acc[4][NF];
#pragma unroll
  for (int a = 0; a < 4; ++a)
#pragma unroll
    for (int b = 0; b < NF; ++b) acc[a][b] = (f32x4){0.f, 0.f, 0.f, 0.f};

  stage(0, 0);
  __syncthreads();
  const int nsteps = K / BK;
  for (int ks = 0; ks < nsteps; ++ks) {
    int cur = ks & 1;
    if (ks + 1 < nsteps) stage(cur ^ 1, (ks + 1) * BK);
    const unsigned short* base = lds[cur];
    bf16x8 ah[4], bh[NF], bl[NF];
#pragma unroll
    for (int fm = 0; fm < 4; ++fm) {
      int row = fm * 16 + lr;
      int p = lk ^ ((row >> 1) & 3);
      ah[fm] = *(const bf16x8*)(base + row * BK + p * 8);
    }
#pragma unroll
    for (int fb = 0; fb < NF; ++fb) {
      int n = w * (BN / 4) + fb * 16 + lr;
      int p = lk ^ ((n >> 1) & 3);
      const unsigned short* b = base + ASZ + n * BK + p * 8;
      bh[fb] = *(const bf16x8*)b;
      bl[fb] = *(const bf16x8*)(b + BSZ);
    }
#pragma unroll
    for (int fm = 0; fm < 4; ++fm)
#pragma unroll
      for (int fb = 0; fb < NF; ++fb) {
        acc[fm][fb] = __builtin_amdgcn_mfma_f32_16x16x32_bf16(ah[fm], bh[fb], acc[fm][fb], 0, 0, 0);
        acc[fm][fb] = __builtin_amdgcn_mfma_f32_16x16x32_bf16(ah[fm], bl[fb], acc[fm][fb], 0, 0, 0);
      }
    __syncthreads();
  }
  // epilogue: C/D layout col=lane&15, row=(lane>>4)*4+reg; g=dinv*acc, sliced
#pragma unroll
  for (int fm = 0; fm < 4; ++fm)
#pragma unroll
    for (int r = 0; r < 4; ++r) {
      int row = m0 + fm * 16 + lk * 4 + r;
      if (row < M) {
        float dv = dinv[row];
#pragma unroll
        for (int fb = 0; fb < NF; ++fb) {
          int col = w * (BN / 4) + fb * 16 + lr;
          size_t o = ((size_t)(col >> 6) * M + row) * 64 + (col & 63);
          Co[o] = f2bf(dv * acc[fm][fb][r]);
        }
      }
    }
}

// ---------------------------------------------------------------------------
// Slice-resident gather-aggregate over pre-scaled bf16 gS, 64-ch slices.
// 32 lanes per node: 4 sub-lanes (stride-4 edge partition) x 8 channel lanes
// (uint4 = 16B each -> 128B line-aligned slice row). v_dot2_f32_bf16 accum.
// Bijective block map: x=bid%8 -> slice=x&(NSL-1), dup=x>>log2(NSL);
// nb=(bid>>3)*DUP+dup. out = dinv[v]*(sum g[src] + g[v]) + b.
// MODE 0: fp32 out.  MODE 1: relu -> bf16 f1 (single precision).
// ---------------------------------------------------------------------------
template <int C, int MODE>
__global__ __launch_bounds__(256) void k_agg_slice(
    const int* __restrict__ rowstart, const int* __restrict__ csr,
    const float* __restrict__ dinv, const unsigned short* __restrict__ gS,
    const float* __restrict__ bias, float* __restrict__ out,
    unsigned short* __restrict__ of1, int N) {
  constexpr int NSL = C / 64;        // 4 (C=256) or 2 (C=128)
  constexpr int DUP = 8 / NSL;       // XCD duplicates per slice
  const int x = blockIdx.x & 7;
  const int slice = x & (NSL - 1);
  const int dup = x >> (NSL == 4 ? 2 : 1);
  const int nb = ((int)blockIdx.x >> 3) * DUP + dup;
  const int v = nb * 8 + ((int)threadIdx.x >> 5);
  if (v >= N) return;
  const int ln = threadIdx.x & 31;
  const int sub = ln >> 3;   // edge sub-stream 0..3
  const int l8 = ln & 7;     // channel octet 0..7
  const unsigned short* __restrict__ base = gS + (size_t)slice * N * 64 + l8 * 8;

  const unsigned selL = 0x00003f80u;  // bf16 pair (lo=1.0, hi=0.0)
  const unsigned selH = 0x3f800000u;  // bf16 pair (lo=0.0, hi=1.0)
  float acc[8] = {0.f, 0.f, 0.f, 0.f, 0.f, 0.f, 0.f, 0.f};
#define DOT2(k, word, sel) \
  asm("v_dot2_f32_bf16 %0, %1, %2, %0" : "+v"(acc[k]) : "v"(word), "v"(sel));
#define ACC8(u)                 \
  { DOT2(0, (u).x, selL) DOT2(1, (u).x, selH)  \
    DOT2(2, (u).y, selL) DOT2(3, (u).y, selH)  \
    DOT2(4, (u).z, selL) DOT2(5, (u).z, selH)  \
    DOT2(6, (u).w, selL) DOT2(7, (u).w, selH) }

  const int end = rowstart[v + 1];
  int j = rowstart[v] + sub;
  for (; j + 4 < end; j += 8) {  // 2 edges per iter per sub-stream
    int s0 = csr[j], s1 = csr[j + 4];
    uint4 r0 = *(const uint4*)(base + (size_t)s0 * 64);
    uint4 r1 = *(const uint4*)(base + (size_t)s1 * 64);
    ACC8(r0) ACC8(r1)
  }
  if (j < end) {
    uint4 r = *(const uint4*)(base + (size_t)csr[j] * 64);
    ACC8(r)
  }
  // reduce the 4 sub-streams within each 32-lane group
#pragma unroll
  for (int k = 0; k < 8; ++k) {
    acc[k] += __shfl_xor(acc[k], 8, 32);
    acc[k] += __shfl_xor(acc[k], 16, 32);
  }
  if (sub != 0) return;
  {  // self-loop
    uint4 r = *(const uint4*)(base + (size_t)v * 64);
    ACC8(r)
  }
#undef ACC8
#undef DOT2
  const float dv = dinv[v];
  const int c0 = slice * 64 + l8 * 8;
  const float4 bA = *(const float4*)(bias + c0);
  const float4 bB = *(const float4*)(bias + c0 + 4);
  float o[8];
  o[0] = dv * acc[0] + bA.x; o[1] = dv * acc[1] + bA.y;
  o[2] = dv * acc[2] + bA.z; o[3] = dv * acc[3] + bA.w;
  o[4] = dv * acc[4] + bB.x; o[5] = dv * acc[5] + bB.y;
  o[6] = dv * acc[6] + bB.z; o[7] = dv * acc[7] + bB.w;
  if constexpr (MODE == 1) {
    u16x8 p;
#pragma unroll
    for (int k = 0; k < 8; ++k) p[k] = f2bf(fmaxf(o[k], 0.f));
    *(u16x8*)(of1 + (size_t)v * C + c0) = p;
  } else {
    *(float4*)(out + (size_t)v * C + c0) = make_float4(o[0], o[1], o[2], o[3]);
    *(float4*)(out + (size_t)v * C + c0 + 4) = make_float4(o[4], o[5], o[6], o[7]);
  }
}

// ---------------------------------------------------------------------------

extern "C" void kernel_launch(void* const* d_in, const int* in_sizes, int n_in,
                              void* d_out, int out_size, void* d_ws, size_t ws_size,
                              hipStream_t stream) {
  const float* x  = (const float*)d_in[0];
  const void*  ei = d_in[1];
  const float* W1 = (const float*)d_in[2];
  const float* b1 = (const float*)d_in[3];
  const float* W2 = (const float*)d_in[4];
  const float* b2 = (const float*)d_in[5];
  float* out = (float*)d_out;

  const int N = in_sizes[0] / CH1;  // 50000
  const int E = in_sizes[1] / 2;    // 800000

  char* w = (char*)d_ws;
  size_t off = 0;
  auto alloc = [&](size_t bytes) -> void* {
    void* p = w + off;
    off += (bytes + 255) & ~(size_t)255;
    return p;
  };
  int*   deg      = (int*)alloc((size_t)N * 4);
  int*   flag     = (int*)alloc(256);
  int*   e32      = (int*)alloc((size_t)2 * E * 4);
  int*   rowstart = (int*)alloc((size_t)(N + 1) * 4);
  int*   cursor   = (int*)alloc((size_t)N * 4);
  int*   bsum     = (int*)alloc(256 * 4);
  int*   csr      = (int*)alloc((size_t)E * 4);
  float* dinv     = (float*)alloc((size_t)N * 4);
  unsigned short* xh  = (unsigned short*)alloc((size_t)N * CH1 * 2);  // also f1
  unsigned short* g1S = (unsigned short*)alloc((size_t)N * CH1 * 2);  // sliced
  unsigned short* g2S = (unsigned short*)alloc((size_t)N * CH2 * 2);  // sliced
  unsigned short* w1th = (unsigned short*)alloc((size_t)CH1 * CH1 * 2);
  unsigned short* w1tl = (unsigned short*)alloc((size_t)CH1 * CH1 * 2);
  unsigned short* w2th = (unsigned short*)alloc((size_t)CH1 * CH2 * 2);
  unsigned short* w2tl = (unsigned short*)alloc((size_t)CH1 * CH2 * 2);

  const int* srcI = e32;
  const int* dstI = e32 + E;

  dim3 blk(256);
  auto cdiv = [](long long a, long long b) { return (int)((a + b - 1) / b); };
  const int nchunks = cdiv(N, 256);
  const int nodeblk8 = cdiv(N, 8);  // 8 nodes per 256-thr block (32 lanes/node)

  // --- CSR build ----------------------------------------------------------
  k_init_deg<<<cdiv(N, 256), blk, 0, stream>>>(deg, N, flag);
  k_detect_i32<<<cdiv(2LL * E, 256), blk, 0, stream>>>((const unsigned int*)ei, 2 * E, flag);
  k_cvt_deg<<<cdiv(2LL * E, 256), blk, 0, stream>>>(ei, e32, deg, E, flag);
  k_chunk_sum<<<nchunks, blk, 0, stream>>>(deg, bsum, N);
  k_scan_bsums<<<1, blk, 0, stream>>>(bsum, nchunks);
  k_chunk_scan<<<nchunks, blk, 0, stream>>>(deg, bsum, rowstart, cursor, dinv, N, E);
  k_fill<<<cdiv(E, 256), blk, 0, stream>>>(srcI, dstI, cursor, csr, E);

  // --- input conversion ---------------------------------------------------
  k_cvt_bf16<<<cdiv((long long)N * CH1 / 8, 256), blk, 0, stream>>>(
      (const float4*)x, (u16x8*)xh, N * CH1 / 8);
  k_splitT2<<<cdiv(CH1 * CH1 + CH1 * CH2, 256), blk, 0, stream>>>(
      W1, w1th, w1tl, CH1, CH1, W2, w2th, w2tl, CH1, CH2);

  // --- layer 1: g1 = dinv*(x@W1) sliced ; f1 = relu(dv*sum+b1) bf16 -> xh --
  k_gemm_mfma<CH1><<<cdiv(N, 64), blk, 0, stream>>>(
      xh, w1th, w1tl, dinv, g1S, N, CH1);
  k_agg_slice<CH1, 1><<<cdiv(nodeblk8, 2) * 8, blk, 0, stream>>>(
      rowstart, csr, dinv, g1S, b1, nullptr, xh, N);

  // --- layer 2: g2 = dinv*(f1@W2) sliced ; out = dv*sum+b2 ----------------
  k_gemm_mfma<CH2><<<cdiv(N, 64), blk, 0, stream>>>(
      xh, w2th, w2tl, dinv, g2S, N, CH1);
  k_agg_slice<CH2, 0><<<cdiv(nodeblk8, 4) * 8, blk, 0, stream>>>(
      rowstart, csr, dinv, g2S, b2, out, nullptr, N);
}

// Round 11
// 244.891 us; speedup vs baseline: 1.0906x; 1.0320x over previous
//
#include <hip/hip_runtime.h>
#include <cstdint>
#include <cstddef>

// ---------------------------------------------------------------------------
// GCN encoder:
//   g[u]  = dinv[u] * h[u]    (folded into GEMM epilogue, bf16, SLICE-MAJOR)
//   out[v]= dinv[v] * (sum_{e:dst=v} g[src] + g[v]) + b
// r11: W stored as single bf16 (lo-half dropped; measured absmax floor
// 1.95e-3 through r10 shows headroom vs 9.2e-3 threshold) -> GEMM does ONE
// MFMA pass per fragment, half the B staging, LDS 72->40 KB.
// Aggregate unchanged from r9 (per-CU miss-service floor, r7-r9 evidence).
// ---------------------------------------------------------------------------

static constexpr int CH1 = 256;
static constexpr int CH2 = 128;

typedef __attribute__((ext_vector_type(8))) short bf16x8;
typedef __attribute__((ext_vector_type(4))) float f32x4;
typedef __attribute__((ext_vector_type(8))) unsigned short u16x8;

__device__ inline unsigned short f2bf(float f) {  // round-to-nearest-even
  unsigned u = __builtin_bit_cast(unsigned, f);
  return (unsigned short)((u + 0x7fffu + ((u >> 16) & 1u)) >> 16);
}
__device__ inline float lo16(unsigned u) { return __builtin_bit_cast(float, u << 16); }
__device__ inline float hi16(unsigned u) { return __builtin_bit_cast(float, u & 0xffff0000u); }

__device__ inline void gload16(const void* g, void* l) {
  __builtin_amdgcn_global_load_lds(
      (const __attribute__((address_space(1))) unsigned int*)g,
      (__attribute__((address_space(3))) unsigned int*)l, 16, 0, 0);
}

// ---------------- preprocessing --------------------------------------------

__global__ void k_init_deg(int* __restrict__ deg, int n, int* __restrict__ flag) {
  int i = blockIdx.x * blockDim.x + threadIdx.x;
  if (i < n) deg[i] = 0;
  if (i == 0) *flag = 0;
}

__global__ void k_detect_i32(const unsigned int* __restrict__ w, int nwords,
                             int* __restrict__ flag) {
  int i = blockIdx.x * blockDim.x + threadIdx.x;
  if (i < nwords && (i & 1) && w[i] != 0u) *flag = 1;
}

// fused convert + degree count (deg must be pre-zeroed)
__global__ void k_cvt_deg(const void* __restrict__ raw, int* __restrict__ e32,
                          int* __restrict__ deg, int E, const int* __restrict__ flag) {
  int i = blockIdx.x * blockDim.x + threadIdx.x;
  if (i >= 2 * E) return;
  int v = (*flag) ? ((const int*)raw)[i] : (int)((const long long*)raw)[i];
  e32[i] = v;
  if (i >= E) atomicAdd(&deg[v], 1);  // dst half
}

__global__ __launch_bounds__(256) void k_chunk_sum(const int* __restrict__ deg,
                                                   int* __restrict__ bsum, int N) {
  __shared__ int sh[256];
  int i = blockIdx.x * 256 + threadIdx.x;
  sh[threadIdx.x] = (i < N) ? deg[i] : 0;
  __syncthreads();
  for (int off = 128; off > 0; off >>= 1) {
    if (threadIdx.x < (unsigned)off) sh[threadIdx.x] += sh[threadIdx.x + off];
    __syncthreads();
  }
  if (threadIdx.x == 0) bsum[blockIdx.x] = sh[0];
}

__global__ __launch_bounds__(256) void k_scan_bsums(int* __restrict__ bsum, int nb) {
  __shared__ int sh[256];
  int t = threadIdx.x;
  int v = (t < nb) ? bsum[t] : 0;
  sh[t] = v;
  __syncthreads();
  for (int off = 1; off < 256; off <<= 1) {
    int add = (t >= off) ? sh[t - off] : 0;
    __syncthreads();
    sh[t] += add;
    __syncthreads();
  }
  if (t < nb) bsum[t] = sh[t] - v;  // exclusive
}

__global__ __launch_bounds__(256) void k_chunk_scan(
    const int* __restrict__ deg, const int* __restrict__ bsum,
    int* __restrict__ rowstart, int* __restrict__ cursor,
    float* __restrict__ dinv, int N, int E) {
  __shared__ int sh[256];
  int t = threadIdx.x;
  int i = blockIdx.x * 256 + t;
  int d = (i < N) ? deg[i] : 0;
  sh[t] = d;
  __syncthreads();
  for (int off = 1; off < 256; off <<= 1) {
    int add = (t >= off) ? sh[t - off] : 0;
    __syncthreads();
    sh[t] += add;
    __syncthreads();
  }
  if (i < N) {
    int rs = bsum[blockIdx.x] + sh[t] - d;
    rowstart[i] = rs;
    cursor[i]   = rs;
    dinv[i] = rsqrtf((float)(d + 1));  // +1: self-loop
  }
  if (i == 0) rowstart[N] = E;
}

__global__ void k_fill(const int* __restrict__ src, const int* __restrict__ dst,
                       int* __restrict__ cursor, int* __restrict__ csr, int E) {
  int e = blockIdx.x * blockDim.x + threadIdx.x;
  if (e < E) {
    int pos = atomicAdd(&cursor[dst[e]], 1);
    csr[pos] = src[e];
  }
}

// ---------------- fused input conversion -----------------------------------
// Range [0, n8x): x fp32 -> bf16, 8 elems/thread.
// Range [n8x, n8x+Ka*Na): W1 -> W1^T bf16.  Then W2 -> W2^T bf16.
__global__ void k_prep(const float4* __restrict__ x, u16x8* __restrict__ xo, int n8x,
                       const float* __restrict__ W1, unsigned short* __restrict__ w1t,
                       int Ka, int Na,
                       const float* __restrict__ W2, unsigned short* __restrict__ w2t,
                       int Kb, int Nb) {
  int i = blockIdx.x * blockDim.x + threadIdx.x;
  if (i < n8x) {
    float4 a = x[i * 2], b = x[i * 2 + 1];
    u16x8 p;
    p[0] = f2bf(a.x); p[1] = f2bf(a.y); p[2] = f2bf(a.z); p[3] = f2bf(a.w);
    p[4] = f2bf(b.x); p[5] = f2bf(b.y); p[6] = f2bf(b.z); p[7] = f2bf(b.w);
    xo[i] = p;
    return;
  }
  i -= n8x;
  if (i < Ka * Na) {
    int k = i / Na, n = i - k * Na;
    w1t[(size_t)n * Ka + k] = f2bf(W1[i]);
    return;
  }
  i -= Ka * Na;
  if (i < Kb * Nb) {
    int k = i / Nb, n = i - k * Nb;
    w2t[(size_t)n * Kb + k] = f2bf(W2[i]);
  }
}

// ---------------------------------------------------------------------------
// bf16 MFMA GEMM: C[M,BN] = A[M,K] @ B[K,BN], A row-major bf16,
// B as B^T bf16 [BN,K] (single precision). fp32 accum.
// Epilogue: g = dinv[row]*acc, stored bf16 SLICE-MAJOR 64ch:
// Co[(col/64)*M*64 + row*64 + col%64].
// BM=64, BK=32, 256 threads (4 waves). LDS double-buffered (40/24 KB),
// global_load_lds 16B staging, 16B-slot XOR swizzle -> 2-way-max conflicts.
// ---------------------------------------------------------------------------
template <int BN>
__global__ __launch_bounds__(256) void k_gemm_mfma(
    const unsigned short* __restrict__ A, const unsigned short* __restrict__ Bt,
    const float* __restrict__ dinv, unsigned short* __restrict__ Co, int M, int K) {
  constexpr int BM = 64, BK = 32;
  constexpr int NF = BN / 64;          // B frags per wave (4 or 2)
  constexpr int ASZ = BM * BK;         // ushorts in A tile
  constexpr int BSZ = BN * BK;         // ushorts in B tile
  __shared__ unsigned short lds[2][ASZ + BSZ];
  const int t = threadIdx.x;
  const int w = t >> 6, l = t & 63;
  const int m0 = blockIdx.x * BM;
  const int lr = l & 15, lk = l >> 4;

  auto stage = [&](int buf, int k0) {
    unsigned short* base = lds[buf];
    {  // A: 256 slots, one per thread
      int row = t >> 2, p = t & 3;
      int s = p ^ ((row >> 1) & 3);
      int gm = m0 + row; if (gm >= M) gm = M - 1;
      gload16(A + (size_t)gm * K + k0 + s * 8, base + (size_t)row * BK + p * 8);
    }
    for (int i = t; i < BN * 4; i += 256) {  // B: BN*4 slots
      int n = i >> 2, p = i & 3;
      int s = p ^ ((n >> 1) & 3);
      gload16(Bt + (size_t)n * K + k0 + s * 8, base + ASZ + (size_t)n * BK + p * 8);
    }
  };

  f32x4 acc[4][NF];
#pragma unroll
  for (int a = 0; a < 4; ++a)
#pragma unroll
    for (int b = 0; b < NF; ++b) acc[a][b] = (f32x4){0.f, 0.f, 0.f, 0.f};

  stage(0, 0);
  __syncthreads();
  const int nsteps = K / BK;
  for (int ks = 0; ks < nsteps; ++ks) {
    int cur = ks & 1;
    if (ks + 1 < nsteps) stage(cur ^ 1, (ks + 1) * BK);
    const unsigned short* base = lds[cur];
    bf16x8 ah[4], bh[NF];
#pragma unroll
    for (int fm = 0; fm < 4; ++fm) {
      int row = fm * 16 + lr;
      int p = lk ^ ((row >> 1) & 3);
      ah[fm] = *(const bf16x8*)(base + row * BK + p * 8);
    }
#pragma unroll
    for (int fb = 0; fb < NF; ++fb) {
      int n = w * (BN / 4) + fb * 16 + lr;
      int p = lk ^ ((n >> 1) & 3);
      bh[fb] = *(const bf16x8*)(base + ASZ + n * BK + p * 8);
    }
#pragma unroll
    for (int fm = 0; fm < 4; ++fm)
#pragma unroll
      for (int fb = 0; fb < NF; ++fb)
        acc[fm][fb] = __builtin_amdgcn_mfma_f32_16x16x32_bf16(ah[fm], bh[fb], acc[fm][fb], 0, 0, 0);
    __syncthreads();
  }
  // epilogue: C/D layout col=lane&15, row=(lane>>4)*4+reg; g=dinv*acc, sliced
#pragma unroll
  for (int fm = 0; fm < 4; ++fm)
#pragma unroll
    for (int r = 0; r < 4; ++r) {
      int row = m0 + fm * 16 + lk * 4 + r;
      if (row < M) {
        float dv = dinv[row];
#pragma unroll
        for (int fb = 0; fb < NF; ++fb) {
          int col = w * (BN / 4) + fb * 16 + lr;
          size_t o = ((size_t)(col >> 6) * M + row) * 64 + (col & 63);
          Co[o] = f2bf(dv * acc[fm][fb][r]);
        }
      }
    }
}

// ---------------------------------------------------------------------------
// Slice-resident gather-aggregate over pre-scaled bf16 gS, 64-ch slices.
// 32 lanes per node: 4 sub-lanes (stride-4 edge partition) x 8 channel lanes
// (uint4 = 16B each -> 128B line-aligned slice row). v_dot2_f32_bf16 accum.
// Bijective block map: x=bid%8 -> slice=x&(NSL-1), dup=x>>log2(NSL);
// nb=(bid>>3)*DUP+dup. out = dinv[v]*(sum g[src] + g[v]) + b.
// MODE 0: fp32 out.  MODE 1: relu -> bf16 f1 (single precision).
// ---------------------------------------------------------------------------
template <int C, int MODE>
__global__ __launch_bounds__(256) void k_agg_slice(
    const int* __restrict__ rowstart, const int* __restrict__ csr,
    const float* __restrict__ dinv, const unsigned short* __restrict__ gS,
    const float* __restrict__ bias, float* __restrict__ out,
    unsigned short* __restrict__ of1, int N) {
  constexpr int NSL = C / 64;        // 4 (C=256) or 2 (C=128)
  constexpr int DUP = 8 / NSL;       // XCD duplicates per slice
  const int x = blockIdx.x & 7;
  const int slice = x & (NSL - 1);
  const int dup = x >> (NSL == 4 ? 2 : 1);
  const int nb = ((int)blockIdx.x >> 3) * DUP + dup;
  const int v = nb * 8 + ((int)threadIdx.x >> 5);
  if (v >= N) return;
  const int ln = threadIdx.x & 31;
  const int sub = ln >> 3;   // edge sub-stream 0..3
  const int l8 = ln & 7;     // channel octet 0..7
  const unsigned short* __restrict__ base = gS + (size_t)slice * N * 64 + l8 * 8;

  const unsigned selL = 0x00003f80u;  // bf16 pair (lo=1.0, hi=0.0)
  const unsigned selH = 0x3f800000u;  // bf16 pair (lo=0.0, hi=1.0)
  float acc[8] = {0.f, 0.f, 0.f, 0.f, 0.f, 0.f, 0.f, 0.f};
#define DOT2(k, word, sel) \
  asm("v_dot2_f32_bf16 %0, %1, %2, %0" : "+v"(acc[k]) : "v"(word), "v"(sel));
#define ACC8(u)                 \
  { DOT2(0, (u).x, selL) DOT2(1, (u).x, selH)  \
    DOT2(2, (u).y, selL) DOT2(3, (u).y, selH)  \
    DOT2(4, (u).z, selL) DOT2(5, (u).z, selH)  \
    DOT2(6, (u).w, selL) DOT2(7, (u).w, selH) }

  const int end = rowstart[v + 1];
  int j = rowstart[v] + sub;
  for (; j + 4 < end; j += 8) {  // 2 edges per iter per sub-stream
    int s0 = csr[j], s1 = csr[j + 4];
    uint4 r0 = *(const uint4*)(base + (size_t)s0 * 64);
    uint4 r1 = *(const uint4*)(base + (size_t)s1 * 64);
    ACC8(r0) ACC8(r1)
  }
  if (j < end) {
    uint4 r = *(const uint4*)(base + (size_t)csr[j] * 64);
    ACC8(r)
  }
  // reduce the 4 sub-streams within each 32-lane group
#pragma unroll
  for (int k = 0; k < 8; ++k) {
    acc[k] += __shfl_xor(acc[k], 8, 32);
    acc[k] += __shfl_xor(acc[k], 16, 32);
  }
  if (sub != 0) return;
  {  // self-loop
    uint4 r = *(const uint4*)(base + (size_t)v * 64);
    ACC8(r)
  }
#undef ACC8
#undef DOT2
  const float dv = dinv[v];
  const int c0 = slice * 64 + l8 * 8;
  const float4 bA = *(const float4*)(bias + c0);
  const float4 bB = *(const float4*)(bias + c0 + 4);
  float o[8];
  o[0] = dv * acc[0] + bA.x; o[1] = dv * acc[1] + bA.y;
  o[2] = dv * acc[2] + bA.z; o[3] = dv * acc[3] + bA.w;
  o[4] = dv * acc[4] + bB.x; o[5] = dv * acc[5] + bB.y;
  o[6] = dv * acc[6] + bB.z; o[7] = dv * acc[7] + bB.w;
  if constexpr (MODE == 1) {
    u16x8 p;
#pragma unroll
    for (int k = 0; k < 8; ++k) p[k] = f2bf(fmaxf(o[k], 0.f));
    *(u16x8*)(of1 + (size_t)v * C + c0) = p;
  } else {
    *(float4*)(out + (size_t)v * C + c0) = make_float4(o[0], o[1], o[2], o[3]);
    *(float4*)(out + (size_t)v * C + c0 + 4) = make_float4(o[4], o[5], o[6], o[7]);
  }
}

// ---------------------------------------------------------------------------

extern "C" void kernel_launch(void* const* d_in, const int* in_sizes, int n_in,
                              void* d_out, int out_size, void* d_ws, size_t ws_size,
                              hipStream_t stream) {
  const float* x  = (const float*)d_in[0];
  const void*  ei = d_in[1];
  const float* W1 = (const float*)d_in[2];
  const float* b1 = (const float*)d_in[3];
  const float* W2 = (const float*)d_in[4];
  const float* b2 = (const float*)d_in[5];
  float* out = (float*)d_out;

  const int N = in_sizes[0] / CH1;  // 50000
  const int E = in_sizes[1] / 2;    // 800000

  char* w = (char*)d_ws;
  size_t off = 0;
  auto alloc = [&](size_t bytes) -> void* {
    void* p = w + off;
    off += (bytes + 255) & ~(size_t)255;
    return p;
  };
  int*   deg      = (int*)alloc((size_t)N * 4);
  int*   flag     = (int*)alloc(256);
  int*   e32      = (int*)alloc((size_t)2 * E * 4);
  int*   rowstart = (int*)alloc((size_t)(N + 1) * 4);
  int*   cursor   = (int*)alloc((size_t)N * 4);
  int*   bsum     = (int*)alloc(256 * 4);
  int*   csr      = (int*)alloc((size_t)E * 4);
  float* dinv     = (float*)alloc((size_t)N * 4);
  unsigned short* xh  = (unsigned short*)alloc((size_t)N * CH1 * 2);  // also f1
  unsigned short* g1S = (unsigned short*)alloc((size_t)N * CH1 * 2);  // sliced
  unsigned short* g2S = (unsigned short*)alloc((size_t)N * CH2 * 2);  // sliced
  unsigned short* w1t = (unsigned short*)alloc((size_t)CH1 * CH1 * 2);
  unsigned short* w2t = (unsigned short*)alloc((size_t)CH1 * CH2 * 2);

  const int* srcI = e32;
  const int* dstI = e32 + E;

  dim3 blk(256);
  auto cdiv = [](long long a, long long b) { return (int)((a + b - 1) / b); };
  const int nchunks = cdiv(N, 256);
  const int nodeblk8 = cdiv(N, 8);  // 8 nodes per 256-thr block (32 lanes/node)
  const int n8x = N * CH1 / 8;

  // --- CSR build ----------------------------------------------------------
  k_init_deg<<<cdiv(N, 256), blk, 0, stream>>>(deg, N, flag);
  k_detect_i32<<<cdiv(2LL * E, 256), blk, 0, stream>>>((const unsigned int*)ei, 2 * E, flag);
  k_cvt_deg<<<cdiv(2LL * E, 256), blk, 0, stream>>>(ei, e32, deg, E, flag);
  k_chunk_sum<<<nchunks, blk, 0, stream>>>(deg, bsum, N);
  k_scan_bsums<<<1, blk, 0, stream>>>(bsum, nchunks);
  k_chunk_scan<<<nchunks, blk, 0, stream>>>(deg, bsum, rowstart, cursor, dinv, N, E);
  k_fill<<<cdiv(E, 256), blk, 0, stream>>>(srcI, dstI, cursor, csr, E);

  // --- input conversion (x -> bf16, W1/W2 -> W^T bf16) --------------------
  k_prep<<<cdiv((long long)n8x + CH1 * CH1 + CH1 * CH2, 256), blk, 0, stream>>>(
      (const float4*)x, (u16x8*)xh, n8x, W1, w1t, CH1, CH1, W2, w2t, CH1, CH2);

  // --- layer 1: g1 = dinv*(x@W1) sliced ; f1 = relu(dv*sum+b1) bf16 -> xh --
  k_gemm_mfma<CH1><<<cdiv(N, 64), blk, 0, stream>>>(xh, w1t, dinv, g1S, N, CH1);
  k_agg_slice<CH1, 1><<<cdiv(nodeblk8, 2) * 8, blk, 0, stream>>>(
      rowstart, csr, dinv, g1S, b1, nullptr, xh, N);

  // --- layer 2: g2 = dinv*(f1@W2) sliced ; out = dv*sum+b2 ----------------
  k_gemm_mfma<CH2><<<cdiv(N, 64), blk, 0, stream>>>(xh, w2t, dinv, g2S, N, CH1);
  k_agg_slice<CH2, 0><<<cdiv(nodeblk8, 4) * 8, blk, 0, stream>>>(
      rowstart, csr, dinv, g2S, b2, out, nullptr, N);
}

// Round 12
// 221.827 us; speedup vs baseline: 1.2040x; 1.1040x over previous
//
#include <hip/hip_runtime.h>
#include <cstdint>
#include <cstddef>

// ---------------------------------------------------------------------------
// GCN encoder:
//   g[u]  = dinv[u] * h[u]    (folded into GEMM epilogue, bf16, SLICE-MAJOR)
//   out[v]= dinv[v] * (sum_{e:dst=v} g[src] + g[v]) + b
// r12: (1) agg_slice -> persistent grid-stride blocks (2048 blocks, slice
// fixed per block for XCD-L2 affinity, ~12 node-groups each) to amortize
// block startup; (2) GEMM tile 128x{256,128}, 512 thr / 8 waves (2Mx4N).
// ---------------------------------------------------------------------------

static constexpr int CH1 = 256;
static constexpr int CH2 = 128;

typedef __attribute__((ext_vector_type(8))) short bf16x8;
typedef __attribute__((ext_vector_type(4))) float f32x4;
typedef __attribute__((ext_vector_type(8))) unsigned short u16x8;

__device__ inline unsigned short f2bf(float f) {  // round-to-nearest-even
  unsigned u = __builtin_bit_cast(unsigned, f);
  return (unsigned short)((u + 0x7fffu + ((u >> 16) & 1u)) >> 16);
}

__device__ inline void gload16(const void* g, void* l) {
  __builtin_amdgcn_global_load_lds(
      (const __attribute__((address_space(1))) unsigned int*)g,
      (__attribute__((address_space(3))) unsigned int*)l, 16, 0, 0);
}

// ---------------- preprocessing --------------------------------------------

__global__ void k_init_deg(int* __restrict__ deg, int n, int* __restrict__ flag) {
  int i = blockIdx.x * blockDim.x + threadIdx.x;
  if (i < n) deg[i] = 0;
  if (i == 0) *flag = 0;
}

__global__ void k_detect_i32(const unsigned int* __restrict__ w, int nwords,
                             int* __restrict__ flag) {
  int i = blockIdx.x * blockDim.x + threadIdx.x;
  if (i < nwords && (i & 1) && w[i] != 0u) *flag = 1;
}

// fused convert + degree count (deg must be pre-zeroed)
__global__ void k_cvt_deg(const void* __restrict__ raw, int* __restrict__ e32,
                          int* __restrict__ deg, int E, const int* __restrict__ flag) {
  int i = blockIdx.x * blockDim.x + threadIdx.x;
  if (i >= 2 * E) return;
  int v = (*flag) ? ((const int*)raw)[i] : (int)((const long long*)raw)[i];
  e32[i] = v;
  if (i >= E) atomicAdd(&deg[v], 1);  // dst half
}

__global__ __launch_bounds__(256) void k_chunk_sum(const int* __restrict__ deg,
                                                   int* __restrict__ bsum, int N) {
  __shared__ int sh[256];
  int i = blockIdx.x * 256 + threadIdx.x;
  sh[threadIdx.x] = (i < N) ? deg[i] : 0;
  __syncthreads();
  for (int off = 128; off > 0; off >>= 1) {
    if (threadIdx.x < (unsigned)off) sh[threadIdx.x] += sh[threadIdx.x + off];
    __syncthreads();
  }
  if (threadIdx.x == 0) bsum[blockIdx.x] = sh[0];
}

__global__ __launch_bounds__(256) void k_scan_bsums(int* __restrict__ bsum, int nb) {
  __shared__ int sh[256];
  int t = threadIdx.x;
  int v = (t < nb) ? bsum[t] : 0;
  sh[t] = v;
  __syncthreads();
  for (int off = 1; off < 256; off <<= 1) {
    int add = (t >= off) ? sh[t - off] : 0;
    __syncthreads();
    sh[t] += add;
    __syncthreads();
  }
  if (t < nb) bsum[t] = sh[t] - v;  // exclusive
}

__global__ __launch_bounds__(256) void k_chunk_scan(
    const int* __restrict__ deg, const int* __restrict__ bsum,
    int* __restrict__ rowstart, int* __restrict__ cursor,
    float* __restrict__ dinv, int N, int E) {
  __shared__ int sh[256];
  int t = threadIdx.x;
  int i = blockIdx.x * 256 + t;
  int d = (i < N) ? deg[i] : 0;
  sh[t] = d;
  __syncthreads();
  for (int off = 1; off < 256; off <<= 1) {
    int add = (t >= off) ? sh[t - off] : 0;
    __syncthreads();
    sh[t] += add;
    __syncthreads();
  }
  if (i < N) {
    int rs = bsum[blockIdx.x] + sh[t] - d;
    rowstart[i] = rs;
    cursor[i]   = rs;
    dinv[i] = rsqrtf((float)(d + 1));  // +1: self-loop
  }
  if (i == 0) rowstart[N] = E;
}

__global__ void k_fill(const int* __restrict__ src, const int* __restrict__ dst,
                       int* __restrict__ cursor, int* __restrict__ csr, int E) {
  int e = blockIdx.x * blockDim.x + threadIdx.x;
  if (e < E) {
    int pos = atomicAdd(&cursor[dst[e]], 1);
    csr[pos] = src[e];
  }
}

// ---------------- fused input conversion -----------------------------------
__global__ void k_prep(const float4* __restrict__ x, u16x8* __restrict__ xo, int n8x,
                       const float* __restrict__ W1, unsigned short* __restrict__ w1t,
                       int Ka, int Na,
                       const float* __restrict__ W2, unsigned short* __restrict__ w2t,
                       int Kb, int Nb) {
  int i = blockIdx.x * blockDim.x + threadIdx.x;
  if (i < n8x) {
    float4 a = x[i * 2], b = x[i * 2 + 1];
    u16x8 p;
    p[0] = f2bf(a.x); p[1] = f2bf(a.y); p[2] = f2bf(a.z); p[3] = f2bf(a.w);
    p[4] = f2bf(b.x); p[5] = f2bf(b.y); p[6] = f2bf(b.z); p[7] = f2bf(b.w);
    xo[i] = p;
    return;
  }
  i -= n8x;
  if (i < Ka * Na) {
    int k = i / Na, n = i - k * Na;
    w1t[(size_t)n * Ka + k] = f2bf(W1[i]);
    return;
  }
  i -= Ka * Na;
  if (i < Kb * Nb) {
    int k = i / Nb, n = i - k * Nb;
    w2t[(size_t)n * Kb + k] = f2bf(W2[i]);
  }
}

// ---------------------------------------------------------------------------
// bf16 MFMA GEMM: C[M,BN] = A[M,K] @ B[K,BN]. BM=128, 512 thr / 8 waves
// (2M x 4N). A row-major bf16, B as B^T bf16 [BN,K]. fp32 accum.
// Epilogue: g = dinv[row]*acc, bf16 SLICE-MAJOR 64ch:
// Co[(col/64)*M*64 + row*64 + col%64].
// LDS double-buffered, global_load_lds 16B staging, 16B-slot XOR swizzle.
// ---------------------------------------------------------------------------
template <int BN>
__global__ __launch_bounds__(512) void k_gemm_mfma(
    const unsigned short* __restrict__ A, const unsigned short* __restrict__ Bt,
    const float* __restrict__ dinv, unsigned short* __restrict__ Co, int M, int K) {
  constexpr int BM = 128, BK = 32;
  constexpr int NF = BN / 64;          // B frags per wave (4 or 2)
  constexpr int ASZ = BM * BK;         // 4096 ushorts
  constexpr int BSZ = BN * BK;
  __shared__ unsigned short lds[2][ASZ + BSZ];
  const int t = threadIdx.x;
  const int w = t >> 6, l = t & 63;
  const int wm = w >> 2, wn = w & 3;   // 2 x 4 wave grid
  const int m0 = blockIdx.x * BM;
  const int lr = l & 15, lk = l >> 4;

  auto stage = [&](int buf, int k0) {
    unsigned short* base = lds[buf];
    {  // A: 512 slots, one per thread
      int row = t >> 2, p = t & 3;
      int s = p ^ ((row >> 1) & 3);
      int gm = m0 + row; if (gm >= M) gm = M - 1;
      gload16(A + (size_t)gm * K + k0 + s * 8, base + (size_t)row * BK + p * 8);
    }
    for (int i = t; i < BN * 4; i += 512) {  // B: BN*4 slots
      int n = i >> 2, p = i & 3;
      int s = p ^ ((n >> 1) & 3);
      gload16(Bt + (size_t)n * K + k0 + s * 8, base + ASZ + (size_t)n * BK + p * 8);
    }
  };

  f32x4 acc[4][NF];
#pragma unroll
  for (int a = 0; a < 4; ++a)
#pragma unroll
    for (int b = 0; b < NF; ++b) acc[a][b] = (f32x4){0.f, 0.f, 0.f, 0.f};

  stage(0, 0);
  __syncthreads();
  const int nsteps = K / BK;
  for (int ks = 0; ks < nsteps; ++ks) {
    int cur = ks & 1;
    if (ks + 1 < nsteps) stage(cur ^ 1, (ks + 1) * BK);
    const unsigned short* base = lds[cur];
    bf16x8 ah[4], bh[NF];
#pragma unroll
    for (int fm = 0; fm < 4; ++fm) {
      int row = wm * 64 + fm * 16 + lr;
      int p = lk ^ ((row >> 1) & 3);
      ah[fm] = *(const bf16x8*)(base + row * BK + p * 8);
    }
#pragma unroll
    for (int fb = 0; fb < NF; ++fb) {
      int n = wn * (BN / 4) + fb * 16 + lr;
      int p = lk ^ ((n >> 1) & 3);
      bh[fb] = *(const bf16x8*)(base + ASZ + n * BK + p * 8);
    }
#pragma unroll
    for (int fm = 0; fm < 4; ++fm)
#pragma unroll
      for (int fb = 0; fb < NF; ++fb)
        acc[fm][fb] = __builtin_amdgcn_mfma_f32_16x16x32_bf16(ah[fm], bh[fb], acc[fm][fb], 0, 0, 0);
    __syncthreads();
  }
  // epilogue: C/D layout col=lane&15, row=(lane>>4)*4+reg; g=dinv*acc, sliced
#pragma unroll
  for (int fm = 0; fm < 4; ++fm)
#pragma unroll
    for (int r = 0; r < 4; ++r) {
      int row = m0 + wm * 64 + fm * 16 + lk * 4 + r;
      if (row < M) {
        float dv = dinv[row];
#pragma unroll
        for (int fb = 0; fb < NF; ++fb) {
          int col = wn * (BN / 4) + fb * 16 + lr;
          size_t o = ((size_t)(col >> 6) * M + row) * 64 + (col & 63);
          Co[o] = f2bf(dv * acc[fm][fb][r]);
        }
      }
    }
}

// ---------------------------------------------------------------------------
// Persistent slice-resident gather-aggregate over pre-scaled bf16 gS (64-ch
// slices, 128B rows). Fixed grid (8*BPS blocks); block keeps one slice
// (x=bid&7 -> XCD-L2 affinity) and grid-strides over node-groups of 8.
// 32 lanes/node: 4 sub-lanes (stride-4 edges) x 8 channel lanes (uint4).
// v_dot2_f32_bf16 accum. out = dinv[v]*(sum g[src] + g[v]) + b.
// MODE 0: fp32 out.  MODE 1: relu -> bf16 f1.
// ---------------------------------------------------------------------------
template <int C, int MODE>
__global__ __launch_bounds__(256) void k_agg_slice(
    const int* __restrict__ rowstart, const int* __restrict__ csr,
    const float* __restrict__ dinv, const unsigned short* __restrict__ gS,
    const float* __restrict__ bias, float* __restrict__ out,
    unsigned short* __restrict__ of1, int N, int nodeblocks) {
  constexpr int NSL = C / 64;        // 4 (C=256) or 2 (C=128)
  constexpr int DUP = 8 / NSL;       // XCD duplicates per slice
  const int x = blockIdx.x & 7;
  const int slice = x & (NSL - 1);
  const int dup = x >> (NSL == 4 ? 2 : 1);
  const int bstride = ((int)gridDim.x >> 3) * DUP;
  const int ln = threadIdx.x & 31;
  const int sub = ln >> 3;   // edge sub-stream 0..3
  const int l8 = ln & 7;     // channel octet 0..7
  const unsigned short* __restrict__ base = gS + (size_t)slice * N * 64 + l8 * 8;
  const int c0 = slice * 64 + l8 * 8;
  const float4 bA = *(const float4*)(bias + c0);      // invariant per block
  const float4 bB = *(const float4*)(bias + c0 + 4);

  const unsigned selL = 0x00003f80u;  // bf16 pair (lo=1.0, hi=0.0)
  const unsigned selH = 0x3f800000u;  // bf16 pair (lo=0.0, hi=1.0)
#define DOT2(k, word, sel) \
  asm("v_dot2_f32_bf16 %0, %1, %2, %0" : "+v"(acc[k]) : "v"(word), "v"(sel));
#define ACC8(u)                 \
  { DOT2(0, (u).x, selL) DOT2(1, (u).x, selH)  \
    DOT2(2, (u).y, selL) DOT2(3, (u).y, selH)  \
    DOT2(4, (u).z, selL) DOT2(5, (u).z, selH)  \
    DOT2(6, (u).w, selL) DOT2(7, (u).w, selH) }

  for (int nb = ((int)blockIdx.x >> 3) * DUP + dup; nb < nodeblocks; nb += bstride) {
    const int v = nb * 8 + ((int)threadIdx.x >> 5);
    if (v >= N) continue;
    float acc[8] = {0.f, 0.f, 0.f, 0.f, 0.f, 0.f, 0.f, 0.f};
    const int end = rowstart[v + 1];
    int j = rowstart[v] + sub;
    for (; j + 4 < end; j += 8) {  // 2 edges per iter per sub-stream
      int s0 = csr[j], s1 = csr[j + 4];
      uint4 r0 = *(const uint4*)(base + (size_t)s0 * 64);
      uint4 r1 = *(const uint4*)(base + (size_t)s1 * 64);
      ACC8(r0) ACC8(r1)
    }
    if (j < end) {
      uint4 r = *(const uint4*)(base + (size_t)csr[j] * 64);
      ACC8(r)
    }
    // reduce the 4 sub-streams within each 32-lane group
#pragma unroll
    for (int k = 0; k < 8; ++k) {
      acc[k] += __shfl_xor(acc[k], 8, 32);
      acc[k] += __shfl_xor(acc[k], 16, 32);
    }
    if (sub == 0) {
      {  // self-loop
        uint4 r = *(const uint4*)(base + (size_t)v * 64);
        ACC8(r)
      }
      const float dv = dinv[v];
      float o[8];
      o[0] = dv * acc[0] + bA.x; o[1] = dv * acc[1] + bA.y;
      o[2] = dv * acc[2] + bA.z; o[3] = dv * acc[3] + bA.w;
      o[4] = dv * acc[4] + bB.x; o[5] = dv * acc[5] + bB.y;
      o[6] = dv * acc[6] + bB.z; o[7] = dv * acc[7] + bB.w;
      if constexpr (MODE == 1) {
        u16x8 p;
#pragma unroll
        for (int k = 0; k < 8; ++k) p[k] = f2bf(fmaxf(o[k], 0.f));
        *(u16x8*)(of1 + (size_t)v * C + c0) = p;
      } else {
        *(float4*)(out + (size_t)v * C + c0) = make_float4(o[0], o[1], o[2], o[3]);
        *(float4*)(out + (size_t)v * C + c0 + 4) = make_float4(o[4], o[5], o[6], o[7]);
      }
    }
  }
#undef ACC8
#undef DOT2
}

// ---------------------------------------------------------------------------

extern "C" void kernel_launch(void* const* d_in, const int* in_sizes, int n_in,
                              void* d_out, int out_size, void* d_ws, size_t ws_size,
                              hipStream_t stream) {
  const float* x  = (const float*)d_in[0];
  const void*  ei = d_in[1];
  const float* W1 = (const float*)d_in[2];
  const float* b1 = (const float*)d_in[3];
  const float* W2 = (const float*)d_in[4];
  const float* b2 = (const float*)d_in[5];
  float* out = (float*)d_out;

  const int N = in_sizes[0] / CH1;  // 50000
  const int E = in_sizes[1] / 2;    // 800000

  char* w = (char*)d_ws;
  size_t off = 0;
  auto alloc = [&](size_t bytes) -> void* {
    void* p = w + off;
    off += (bytes + 255) & ~(size_t)255;
    return p;
  };
  int*   deg      = (int*)alloc((size_t)N * 4);
  int*   flag     = (int*)alloc(256);
  int*   e32      = (int*)alloc((size_t)2 * E * 4);
  int*   rowstart = (int*)alloc((size_t)(N + 1) * 4);
  int*   cursor   = (int*)alloc((size_t)N * 4);
  int*   bsum     = (int*)alloc(256 * 4);
  int*   csr      = (int*)alloc((size_t)E * 4);
  float* dinv     = (float*)alloc((size_t)N * 4);
  unsigned short* xh  = (unsigned short*)alloc((size_t)N * CH1 * 2);  // also f1
  unsigned short* g1S = (unsigned short*)alloc((size_t)N * CH1 * 2);  // sliced
  unsigned short* g2S = (unsigned short*)alloc((size_t)N * CH2 * 2);  // sliced
  unsigned short* w1t = (unsigned short*)alloc((size_t)CH1 * CH1 * 2);
  unsigned short* w2t = (unsigned short*)alloc((size_t)CH1 * CH2 * 2);

  const int* srcI = e32;
  const int* dstI = e32 + E;

  dim3 blk(256), blk512(512);
  auto cdiv = [](long long a, long long b) { return (int)((a + b - 1) / b); };
  const int nchunks = cdiv(N, 256);
  const int nodeblocks = cdiv(N, 8);   // 6250
  const int n8x = N * CH1 / 8;
  const int AGG_GRID = 2048;           // 8 blocks/CU, slice-affine persistent

  // --- CSR build ----------------------------------------------------------
  k_init_deg<<<cdiv(N, 256), blk, 0, stream>>>(deg, N, flag);
  k_detect_i32<<<cdiv(2LL * E, 256), blk, 0, stream>>>((const unsigned int*)ei, 2 * E, flag);
  k_cvt_deg<<<cdiv(2LL * E, 256), blk, 0, stream>>>(ei, e32, deg, E, flag);
  k_chunk_sum<<<nchunks, blk, 0, stream>>>(deg, bsum, N);
  k_scan_bsums<<<1, blk, 0, stream>>>(bsum, nchunks);
  k_chunk_scan<<<nchunks, blk, 0, stream>>>(deg, bsum, rowstart, cursor, dinv, N, E);
  k_fill<<<cdiv(E, 256), blk, 0, stream>>>(srcI, dstI, cursor, csr, E);

  // --- input conversion (x -> bf16, W1/W2 -> W^T bf16) --------------------
  k_prep<<<cdiv((long long)n8x + CH1 * CH1 + CH1 * CH2, 256), blk, 0, stream>>>(
      (const float4*)x, (u16x8*)xh, n8x, W1, w1t, CH1, CH1, W2, w2t, CH1, CH2);

  // --- layer 1: g1 = dinv*(x@W1) sliced ; f1 = relu(dv*sum+b1) bf16 -> xh --
  k_gemm_mfma<CH1><<<cdiv(N, 128), blk512, 0, stream>>>(xh, w1t, dinv, g1S, N, CH1);
  k_agg_slice<CH1, 1><<<AGG_GRID, blk, 0, stream>>>(
      rowstart, csr, dinv, g1S, b1, nullptr, xh, N, nodeblocks);

  // --- layer 2: g2 = dinv*(f1@W2) sliced ; out = dv*sum+b2 ----------------
  k_gemm_mfma<CH2><<<cdiv(N, 128), blk512, 0, stream>>>(xh, w2t, dinv, g2S, N, CH1);
  k_agg_slice<CH2, 0><<<AGG_GRID, blk, 0, stream>>>(
      rowstart, csr, dinv, g2S, b2, out, nullptr, N, nodeblocks);
}